// Round 4
// baseline (344.800 us; speedup 1.0000x reference)
//
#include <hip/hip_runtime.h>
#include <hip/hip_bf16.h>

typedef __bf16  bf16x8 __attribute__((ext_vector_type(8)));
typedef float   f32x4  __attribute__((ext_vector_type(4)));
using bf16 = __hip_bfloat16;

#define MFMA16(A_, B_, C_) __builtin_amdgcn_mfma_f32_16x16x32_bf16((A_), (B_), (C_), 0, 0, 0)

// Problem constants: B=4, T=2048, C=1024, H=16, D=64. M = B*T = 8192, K = N = 1024.

// --- async global->LDS, 16B per lane (m97 pattern) ---------------------------
__device__ __forceinline__ void gll16(const void* g, void* l) {
    __builtin_amdgcn_global_load_lds(
        (const __attribute__((address_space(1))) void*)g,
        (__attribute__((address_space(3))) void*)l, 16, 0, 0);
}

// --- staging helpers (fallback path) ----------------------------------------
__device__ inline void stage8(bf16* dst, const float* src) {
    const float4 a = *(const float4*)(src);
    const float4 b = *(const float4*)(src + 4);
    union { int4 v; bf16 h[8]; } u;
    u.h[0] = __float2bfloat16(a.x); u.h[1] = __float2bfloat16(a.y);
    u.h[2] = __float2bfloat16(a.z); u.h[3] = __float2bfloat16(a.w);
    u.h[4] = __float2bfloat16(b.x); u.h[5] = __float2bfloat16(b.y);
    u.h[6] = __float2bfloat16(b.z); u.h[7] = __float2bfloat16(b.w);
    *(int4*)dst = u.v;
}
__device__ inline void stage8(bf16* dst, const bf16* src) {
    *(int4*)dst = *(const int4*)src;
}
__device__ inline void store_out(float* p, float v) { *p = v; }
__device__ inline void store_out(bf16*  p, float v) { *p = __float2bfloat16(v); }

// ---------------------------------------------------------------------------
// fp32 -> bf16 convert: x (8M elems) + 4 weight matrices (1M each)
// ---------------------------------------------------------------------------
__global__ __launch_bounds__(256) void cvt_bf16(const float* __restrict__ x,
    const float* __restrict__ W0, const float* __restrict__ W1,
    const float* __restrict__ W2, const float* __restrict__ W3,
    bf16* __restrict__ xb, bf16* __restrict__ Wb)
{
    const size_t nx4 = 2097152;              // 8M / 4
    const size_t total4 = nx4 + 4 * 262144;  // + 4M / 4
    for (size_t v = (size_t)blockIdx.x * 256 + threadIdx.x; v < total4;
         v += (size_t)gridDim.x * 256) {
        const float* src; bf16* dst; size_t off;
        if (v < nx4) { src = x; dst = xb; off = v * 4; }
        else {
            const size_t vw = v - nx4;
            const int w = (int)(vw >> 18);
            off = (vw & 262143) * 4;
            src = (w == 0) ? W0 : (w == 1) ? W1 : (w == 2) ? W2 : W3;
            dst = Wb + ((size_t)w << 20);
        }
        const float4 f = *(const float4*)(src + off);
        union { bf16 h[4]; uint2 u; } pk;
        pk.h[0] = __float2bfloat16(f.x); pk.h[1] = __float2bfloat16(f.y);
        pk.h[2] = __float2bfloat16(f.z); pk.h[3] = __float2bfloat16(f.w);
        *(uint2*)(dst + off) = pk.u;
    }
}

// ---------------------------------------------------------------------------
// bf16 GEMM v2: BK=64, XOR-swizzled LDS (conflict-free ds_read_b128 under the
// gll16 no-padding constraint), 32 MFMA per barrier-pair.
// out = A[8192][1024] @ Bm[N=1024][1024]^T + bias; 128x128 tile.
// blockIdx.z selects (Bm,bias,out,mode): mode 0: f32 row-major [8192][1024];
// mode 1: bf16 [B][H][T][D]; mode 2: bf16 [B][H][D][T] (packed 8B stores).
// ---------------------------------------------------------------------------
struct GemmArgs {
    const bf16*  Bm[3];
    const float* bias[3];
    void*        out[3];
    int          mode[3];
};

__global__ __launch_bounds__(256) void gemm_bb(const bf16* __restrict__ A, GemmArgs ga)
{
    __shared__ __align__(16) bf16 sA[128 * 64];
    __shared__ __align__(16) bf16 sB[128 * 64];
    const int z = blockIdx.z;
    const bf16*  __restrict__ Bm   = ga.Bm[z];
    const float* __restrict__ bias = ga.bias[z];
    const int mode = ga.mode[z];
    const int tid  = threadIdx.x;
    const int lane = tid & 63;
    const int wave = tid >> 6;
    const int l15  = lane & 15;
    const int quad = lane >> 4;
    const int m0 = blockIdx.x * 128;
    const int n0 = blockIdx.y * 128;
    const int wm = (wave >> 1) * 64;
    const int wn = (wave & 1) * 64;

    f32x4 acc[4][4] = {};

    for (int k0 = 0; k0 < 1024; k0 += 64) {
#pragma unroll
        for (int s = 0; s < 4; ++s) {
            const int L = s * 256 + tid;
            const int r = L >> 3, kl = L & 7;
            const int kg = (kl ^ (r & 7)) * 8;
            gll16(A  + (size_t)(m0 + r) * 1024 + k0 + kg, &sA[L * 8]);
            gll16(Bm + (size_t)(n0 + r) * 1024 + k0 + kg, &sB[L * 8]);
        }
        __syncthreads();

#pragma unroll
        for (int kstep = 0; kstep < 2; ++kstep) {
            const int cs = ((quad + 4 * kstep) ^ (l15 & 7)) * 8;
            bf16x8 aF[4], bF[4];
#pragma unroll
            for (int i = 0; i < 4; ++i)
                aF[i] = *(const bf16x8*)&sA[(wm + i * 16 + l15) * 64 + cs];
#pragma unroll
            for (int j = 0; j < 4; ++j)
                bF[j] = *(const bf16x8*)&sB[(wn + j * 16 + l15) * 64 + cs];
#pragma unroll
            for (int i = 0; i < 4; ++i)
#pragma unroll
                for (int j = 0; j < 4; ++j)
                    acc[i][j] = MFMA16(aF[i], bF[j], acc[i][j]);
        }
        __syncthreads();
    }

    if (mode == 2) {
        bf16* ob = (bf16*)ga.out[z];
#pragma unroll
        for (int j = 0; j < 4; ++j) {
            const int col = n0 + wn + j * 16 + l15;
            const float bv = bias[col];
            const int h = col >> 6, d = col & 63;
#pragma unroll
            for (int i = 0; i < 4; ++i) {
                const int row0 = m0 + wm + i * 16 + quad * 4;
                const int b = row0 >> 11, t = row0 & 2047;
                union { bf16 hh[4]; uint2 v; } pk;
#pragma unroll
                for (int r = 0; r < 4; ++r)
                    pk.hh[r] = __float2bfloat16(acc[i][j][r] + bv);
                *(uint2*)&ob[((size_t)(b * 16 + h) * 64 + d) * 2048 + t] = pk.v;
            }
        }
    } else if (mode == 1) {
        bf16* ob = (bf16*)ga.out[z];
#pragma unroll
        for (int j = 0; j < 4; ++j) {
            const int col = n0 + wn + j * 16 + l15;
            const float bv = bias[col];
            const int h = col >> 6, d = col & 63;
#pragma unroll
            for (int i = 0; i < 4; ++i) {
#pragma unroll
                for (int r = 0; r < 4; ++r) {
                    const int row = m0 + wm + i * 16 + quad * 4 + r;
                    const int b = row >> 11, t = row & 2047;
                    ob[((size_t)(b * 16 + h) * 2048 + t) * 64 + d] =
                        __float2bfloat16(acc[i][j][r] + bv);
                }
            }
        }
    } else {
        float* of = (float*)ga.out[z];
#pragma unroll
        for (int j = 0; j < 4; ++j) {
            const int col = n0 + wn + j * 16 + l15;
            const float bv = bias[col];
#pragma unroll
            for (int i = 0; i < 4; ++i) {
#pragma unroll
                for (int r = 0; r < 4; ++r) {
                    const int row = m0 + wm + i * 16 + quad * 4 + r;
                    of[(size_t)row * 1024 + col] = acc[i][j][r] + bv;
                }
            }
        }
    }
}

// ---------------------------------------------------------------------------
// Fallback GEMM (fp32 staging through VGPRs) — proven Round-2 path.
// ---------------------------------------------------------------------------
template <int MODE, typename AT, typename OT>
__global__ __launch_bounds__(256) void gemm_bt(const AT* __restrict__ A,
                                               const float* __restrict__ Bm,
                                               const float* __restrict__ bias,
                                               OT* __restrict__ Cout)
{
    __shared__ __align__(16) bf16 sA[128 * 32];
    __shared__ __align__(16) bf16 sB[128 * 32];
    const int tid  = threadIdx.x;
    const int lane = tid & 63;
    const int wave = tid >> 6;
    const int l15  = lane & 15;
    const int quad = lane >> 4;
    const int m0 = blockIdx.x * 128;
    const int n0 = blockIdx.y * 128;
    const int wm = (wave >> 1) * 64;
    const int wn = (wave & 1) * 64;

    f32x4 acc[4][4] = {};

    const int c0 = tid, c1 = tid + 256;
    const size_t aoff0 = (size_t)(m0 + (c0 >> 2)) * 1024 + (c0 & 3) * 8;
    const size_t aoff1 = (size_t)(m0 + (c1 >> 2)) * 1024 + (c1 & 3) * 8;
    const size_t boff0 = (size_t)(n0 + (c0 >> 2)) * 1024 + (c0 & 3) * 8;
    const size_t boff1 = (size_t)(n0 + (c1 >> 2)) * 1024 + (c1 & 3) * 8;

    for (int k0 = 0; k0 < 1024; k0 += 32) {
        stage8(&sA[c0 * 8], A  + aoff0 + k0);
        stage8(&sA[c1 * 8], A  + aoff1 + k0);
        stage8(&sB[c0 * 8], Bm + boff0 + k0);
        stage8(&sB[c1 * 8], Bm + boff1 + k0);
        __syncthreads();

        bf16x8 aF[4], bF[4];
#pragma unroll
        for (int i = 0; i < 4; ++i)
            aF[i] = *(const bf16x8*)&sA[(wm + i * 16 + l15) * 32 + quad * 8];
#pragma unroll
        for (int j = 0; j < 4; ++j)
            bF[j] = *(const bf16x8*)&sB[(wn + j * 16 + l15) * 32 + quad * 8];
#pragma unroll
        for (int i = 0; i < 4; ++i)
#pragma unroll
            for (int j = 0; j < 4; ++j)
                acc[i][j] = MFMA16(aF[i], bF[j], acc[i][j]);
        __syncthreads();
    }

#pragma unroll
    for (int j = 0; j < 4; ++j) {
        const int col = n0 + wn + j * 16 + l15;
        const float bv = bias[col];
#pragma unroll
        for (int i = 0; i < 4; ++i) {
#pragma unroll
            for (int r = 0; r < 4; ++r) {
                const int row = m0 + wm + i * 16 + quad * 4 + r;
                const float v = acc[i][j][r] + bv;
                size_t idx;
                if (MODE == 0) idx = (size_t)row * 1024 + col;
                else {
                    const int b = row >> 11, t = row & 2047;
                    const int h = col >> 6,  d = col & 63;
                    if (MODE == 1) idx = ((size_t)(b * 16 + h) * 2048 + t) * 64 + d;
                    else           idx = ((size_t)(b * 16 + h) * 64 + d) * 2048 + t;
                }
                store_out(&Cout[idx], v);
            }
        }
    }
}

// ---------------------------------------------------------------------------
// Flash attention v3: K-tile = 128 (half the barriers of v2), S^T = K·Q^T,
// un-maxed exp2 softmax, padded conflict-free LDS, triangular pairing.
// Q,K: [B][H][T][64]; Vt: [B][H][64][T]; Y: [B][T][C] (all bf16).
// Grid (16, 64), block 256 (4 waves x 16 q-rows). LDS 52 KB -> 3 blocks/CU.
// ---------------------------------------------------------------------------
__global__ __launch_bounds__(256) void attn_fwd3(const bf16* __restrict__ Q,
                                                 const bf16* __restrict__ K,
                                                 const bf16* __restrict__ Vt,
                                                 bf16* __restrict__ Y)
{
    __shared__ __align__(16) bf16 sK[128 * 72];
    __shared__ __align__(16) bf16 sV[64 * 136];      // [d][t], t-tile 128 + pad
    __shared__ __align__(16) bf16 sP[4][16 * 136];   // per-wave P^T [q][t]
    const int tid  = threadIdx.x;
    const int lane = tid & 63;
    const int wave = tid >> 6;
    const int l15  = lane & 15;
    const int quad = lane >> 4;
    const int bh = blockIdx.y;
    const size_t headQK = (size_t)bh * 2048 * 64;
    const size_t headV  = (size_t)bh * 64 * 2048;
    const int b = bh >> 4, h = bh & 15;
    constexpr float cscale = 0.125f * 1.44269504088896340736f;  // scale * log2(e)

    bf16* sPw = sP[wave];

#pragma unroll
    for (int strip = 0; strip < 2; ++strip) {
        const int qt = strip ? (31 - (int)blockIdx.x) : (int)blockIdx.x;
        const int q0 = qt * 64;
        const int myq = q0 + wave * 16 + l15;

        const bf16* qrow = Q + headQK + (size_t)myq * 64;
        const bf16x8 qF0 = *(const bf16x8*)(qrow + quad * 8);
        const bf16x8 qF1 = *(const bf16x8*)(qrow + 32 + quad * 8);

        float l_part = 0.f;
        f32x4 O[4] = {};   // O^T: lane holds q=l15, d = jd*16 + quad*4 + r

        for (int t0 = 0; t0 <= q0; t0 += 128) {
#pragma unroll
            for (int s = 0; s < 4; ++s) {
                const int cK = s * 256 + tid;
                const int rK = cK >> 3, kK = (cK & 7) * 8;
                *(int4*)&sK[rK * 72 + kK] =
                    *(const int4*)(K + headQK + (size_t)(t0 + rK) * 64 + kK);
                const int rV = cK >> 4, kV = (cK & 15) * 8;
                *(int4*)&sV[rV * 136 + kV] =
                    *(const int4*)(Vt + headV + (size_t)rV * 2048 + t0 + kV);
            }
            __syncthreads();

            const bool msk = (t0 + 128 > q0);
#pragma unroll
            for (int j = 0; j < 8; ++j) {
                // S^T sub-tile: A = K rows (m = t), B = Q rows (n = q)
                const bf16x8 kF0 = *(const bf16x8*)&sK[(j * 16 + l15) * 72 + quad * 8];
                const bf16x8 kF1 = *(const bf16x8*)&sK[(j * 16 + l15) * 72 + 32 + quad * 8];
                f32x4 zS = {};
                zS = MFMA16(kF0, qF0, zS);
                zS = MFMA16(kF1, qF1, zS);
                union { bf16 hh[4]; uint2 v; } pk;
#pragma unroll
                for (int r = 0; r < 4; ++r) {
                    float p = exp2f(zS[r] * cscale);
                    if (msk && (t0 + j * 16 + quad * 4 + r) > myq) p = 0.f;
                    l_part += p;
                    pk.hh[r] = __float2bfloat16(p);
                }
                *(uint2*)&sPw[l15 * 136 + j * 16 + quad * 4] = pk.v;
            }

            // O^T += V^T · P^T
            bf16x8 pF[4];
#pragma unroll
            for (int kk = 0; kk < 4; ++kk)
                pF[kk] = *(const bf16x8*)&sPw[l15 * 136 + kk * 32 + quad * 8];
#pragma unroll
            for (int jd = 0; jd < 4; ++jd) {
#pragma unroll
                for (int kk = 0; kk < 4; ++kk) {
                    const bf16x8 vF =
                        *(const bf16x8*)&sV[(jd * 16 + l15) * 136 + kk * 32 + quad * 8];
                    O[jd] = MFMA16(vF, pF[kk], O[jd]);
                }
            }
            __syncthreads();
        }

        l_part += __shfl_xor(l_part, 16);
        l_part += __shfl_xor(l_part, 32);
        const float inv_l = 1.0f / l_part;

        bf16* yrow = Y + ((size_t)(b * 2048 + myq)) * 1024 + h * 64;
#pragma unroll
        for (int jd = 0; jd < 4; ++jd) {
            union { bf16 hh[4]; uint2 v; } ok;
#pragma unroll
            for (int r = 0; r < 4; ++r)
                ok.hh[r] = __float2bfloat16(O[jd][r] * inv_l);
            *(uint2*)&yrow[jd * 16 + quad * 4] = ok.v;
        }
    }
}

// ---------------------------------------------------------------------------
extern "C" void kernel_launch(void* const* d_in, const int* in_sizes, int n_in,
                              void* d_out, int out_size, void* d_ws, size_t ws_size,
                              hipStream_t stream)
{
    const float* x  = (const float*)d_in[0];
    const float* Wq = (const float*)d_in[1];
    const float* bq = (const float*)d_in[2];
    const float* Wk = (const float*)d_in[3];
    const float* bk = (const float*)d_in[4];
    const float* Wv = (const float*)d_in[5];
    const float* bv = (const float*)d_in[6];
    const float* Wp = (const float*)d_in[7];
    const float* bp = (const float*)d_in[8];
    float* out = (float*)d_out;
    bf16*  ws  = (bf16*)d_ws;

    constexpr size_t NE = (size_t)8192 * 1024;  // 8M elems per [B,T,C] tensor
    bf16* Qw = ws;
    bf16* Kw = ws + NE;
    bf16* Vw = ws + 2 * NE;      // [B][H][D][T]
    dim3 bb(256);

    if (ws_size >= (size_t)36 * 1024 * 1024 * 2) {
        bf16* xb = ws + 3 * NE;                  // aliased with Yw (x dead after QKV)
        bf16* Wb = ws + 4 * NE;                  // 4 x 1M bf16 weights
        bf16* Yw = xb;

        cvt_bf16<<<dim3(1024), bb, 0, stream>>>(x, Wq, Wk, Wv, Wp, xb, Wb);

        GemmArgs gq;
        gq.Bm[0] = Wb;    gq.Bm[1] = Wb + (1u << 20);  gq.Bm[2] = Wb + (2u << 20);
        gq.bias[0] = bq;  gq.bias[1] = bk;             gq.bias[2] = bv;
        gq.out[0] = Qw;   gq.out[1] = Kw;              gq.out[2] = Vw;
        gq.mode[0] = 1;   gq.mode[1] = 1;              gq.mode[2] = 2;
        gemm_bb<<<dim3(64, 8, 3), bb, 0, stream>>>(xb, gq);

        attn_fwd3<<<dim3(16, 64), bb, 0, stream>>>(Qw, Kw, Vw, Yw);

        GemmArgs go;
        go.Bm[0] = go.Bm[1] = go.Bm[2] = Wb + ((size_t)3 << 20);
        go.bias[0] = go.bias[1] = go.bias[2] = bp;
        go.out[0] = go.out[1] = go.out[2] = out;
        go.mode[0] = go.mode[1] = go.mode[2] = 0;
        gemm_bb<<<dim3(64, 8, 1), bb, 0, stream>>>(Yw, go);
    } else {
        bf16* Yw = ws + 3 * NE;
        dim3 gg(64, 8);
        gemm_bt<1, float, bf16><<<gg, bb, 0, stream>>>(x, Wq, bq, Qw);
        gemm_bt<1, float, bf16><<<gg, bb, 0, stream>>>(x, Wk, bk, Kw);
        gemm_bt<2, float, bf16><<<gg, bb, 0, stream>>>(x, Wv, bv, Vw);
        attn_fwd3<<<dim3(16, 64), bb, 0, stream>>>(Qw, Kw, Vw, Yw);
        gemm_bt<0, bf16, float><<<gg, bb, 0, stream>>>(Yw, Wp, bp, out);
    }
}

// Round 5
// 282.985 us; speedup vs baseline: 1.2184x; 1.2184x over previous
//
#include <hip/hip_runtime.h>
#include <hip/hip_bf16.h>

typedef __bf16  bf16x8 __attribute__((ext_vector_type(8)));
typedef float   f32x4  __attribute__((ext_vector_type(4)));
using bf16 = __hip_bfloat16;

#define MFMA16(A_, B_, C_) __builtin_amdgcn_mfma_f32_16x16x32_bf16((A_), (B_), (C_), 0, 0, 0)

// Problem constants: B=4, T=2048, C=1024, H=16, D=64. M = B*T = 8192, K = N = 1024.

// --- async global->LDS, 16B per lane (m97 pattern) ---------------------------
__device__ __forceinline__ void gll16(const void* g, void* l) {
    __builtin_amdgcn_global_load_lds(
        (const __attribute__((address_space(1))) void*)g,
        (__attribute__((address_space(3))) void*)l, 16, 0, 0);
}

// --- staging helpers (fallback path) ----------------------------------------
__device__ inline void stage8(bf16* dst, const float* src) {
    const float4 a = *(const float4*)(src);
    const float4 b = *(const float4*)(src + 4);
    union { int4 v; bf16 h[8]; } u;
    u.h[0] = __float2bfloat16(a.x); u.h[1] = __float2bfloat16(a.y);
    u.h[2] = __float2bfloat16(a.z); u.h[3] = __float2bfloat16(a.w);
    u.h[4] = __float2bfloat16(b.x); u.h[5] = __float2bfloat16(b.y);
    u.h[6] = __float2bfloat16(b.z); u.h[7] = __float2bfloat16(b.w);
    *(int4*)dst = u.v;
}
__device__ inline void stage8(bf16* dst, const bf16* src) {
    *(int4*)dst = *(const int4*)src;
}
__device__ inline void store_out(float* p, float v) { *p = v; }
__device__ inline void store_out(bf16*  p, float v) { *p = __float2bfloat16(v); }

// ---------------------------------------------------------------------------
// fp32 -> bf16 convert: x (8M elems) + 4 weight matrices (1M each)
// ---------------------------------------------------------------------------
__global__ __launch_bounds__(256) void cvt_bf16(const float* __restrict__ x,
    const float* __restrict__ W0, const float* __restrict__ W1,
    const float* __restrict__ W2, const float* __restrict__ W3,
    bf16* __restrict__ xb, bf16* __restrict__ Wb)
{
    const size_t nx4 = 2097152;              // 8M / 4
    const size_t total4 = nx4 + 4 * 262144;  // + 4M / 4
    for (size_t v = (size_t)blockIdx.x * 256 + threadIdx.x; v < total4;
         v += (size_t)gridDim.x * 256) {
        const float* src; bf16* dst; size_t off;
        if (v < nx4) { src = x; dst = xb; off = v * 4; }
        else {
            const size_t vw = v - nx4;
            const int w = (int)(vw >> 18);
            off = (vw & 262143) * 4;
            src = (w == 0) ? W0 : (w == 1) ? W1 : (w == 2) ? W2 : W3;
            dst = Wb + ((size_t)w << 20);
        }
        const float4 f = *(const float4*)(src + off);
        union { bf16 h[4]; uint2 u; } pk;
        pk.h[0] = __float2bfloat16(f.x); pk.h[1] = __float2bfloat16(f.y);
        pk.h[2] = __float2bfloat16(f.z); pk.h[3] = __float2bfloat16(f.w);
        *(uint2*)(dst + off) = pk.u;
    }
}

// ---------------------------------------------------------------------------
// bf16 GEMM: BK=64, XOR-swizzled LDS, 32 MFMA per barrier-pair.
// 1D grid, XCD-swizzled: id = z*512 + n*64 + m  ->  all 8 n-blocks of one
// m-strip share id%8 (same XCD) -> A-strip fetched once per XCD.
// mode 0: f32 row-major; 1: bf16 [B][H][T][D]; 2: bf16 [B][H][D][T].
// ---------------------------------------------------------------------------
struct GemmArgs {
    const bf16*  Bm[3];
    const float* bias[3];
    void*        out[3];
    int          mode[3];
};

__global__ __launch_bounds__(256) void gemm_bb(const bf16* __restrict__ A, GemmArgs ga)
{
    __shared__ __align__(16) bf16 sA[128 * 64];
    __shared__ __align__(16) bf16 sB[128 * 64];
    const int id  = blockIdx.x;
    const int z   = id >> 9;
    const int rem = id & 511;
    const int m0 = (rem & 63) * 128;
    const int n0 = (rem >> 6) * 128;
    const bf16*  __restrict__ Bm   = ga.Bm[z];
    const float* __restrict__ bias = ga.bias[z];
    const int mode = ga.mode[z];
    const int tid  = threadIdx.x;
    const int lane = tid & 63;
    const int wave = tid >> 6;
    const int l15  = lane & 15;
    const int quad = lane >> 4;
    const int wm = (wave >> 1) * 64;
    const int wn = (wave & 1) * 64;

    f32x4 acc[4][4] = {};

    for (int k0 = 0; k0 < 1024; k0 += 64) {
#pragma unroll
        for (int s = 0; s < 4; ++s) {
            const int L = s * 256 + tid;
            const int r = L >> 3, kl = L & 7;
            const int kg = (kl ^ (r & 7)) * 8;
            gll16(A  + (size_t)(m0 + r) * 1024 + k0 + kg, &sA[L * 8]);
            gll16(Bm + (size_t)(n0 + r) * 1024 + k0 + kg, &sB[L * 8]);
        }
        __syncthreads();

#pragma unroll
        for (int kstep = 0; kstep < 2; ++kstep) {
            const int cs = ((quad + 4 * kstep) ^ (l15 & 7)) * 8;
            bf16x8 aF[4], bF[4];
#pragma unroll
            for (int i = 0; i < 4; ++i)
                aF[i] = *(const bf16x8*)&sA[(wm + i * 16 + l15) * 64 + cs];
#pragma unroll
            for (int j = 0; j < 4; ++j)
                bF[j] = *(const bf16x8*)&sB[(wn + j * 16 + l15) * 64 + cs];
#pragma unroll
            for (int i = 0; i < 4; ++i)
#pragma unroll
                for (int j = 0; j < 4; ++j)
                    acc[i][j] = MFMA16(aF[i], bF[j], acc[i][j]);
        }
        __syncthreads();
    }

    if (mode == 2) {
        bf16* ob = (bf16*)ga.out[z];
#pragma unroll
        for (int j = 0; j < 4; ++j) {
            const int col = n0 + wn + j * 16 + l15;
            const float bv = bias[col];
            const int h = col >> 6, d = col & 63;
#pragma unroll
            for (int i = 0; i < 4; ++i) {
                const int row0 = m0 + wm + i * 16 + quad * 4;
                const int b = row0 >> 11, t = row0 & 2047;
                union { bf16 hh[4]; uint2 v; } pk;
#pragma unroll
                for (int r = 0; r < 4; ++r)
                    pk.hh[r] = __float2bfloat16(acc[i][j][r] + bv);
                *(uint2*)&ob[((size_t)(b * 16 + h) * 64 + d) * 2048 + t] = pk.v;
            }
        }
    } else if (mode == 1) {
        bf16* ob = (bf16*)ga.out[z];
#pragma unroll
        for (int j = 0; j < 4; ++j) {
            const int col = n0 + wn + j * 16 + l15;
            const float bv = bias[col];
            const int h = col >> 6, d = col & 63;
#pragma unroll
            for (int i = 0; i < 4; ++i) {
#pragma unroll
                for (int r = 0; r < 4; ++r) {
                    const int row = m0 + wm + i * 16 + quad * 4 + r;
                    const int b = row >> 11, t = row & 2047;
                    ob[((size_t)(b * 16 + h) * 2048 + t) * 64 + d] =
                        __float2bfloat16(acc[i][j][r] + bv);
                }
            }
        }
    } else {
        float* of = (float*)ga.out[z];
#pragma unroll
        for (int j = 0; j < 4; ++j) {
            const int col = n0 + wn + j * 16 + l15;
            const float bv = bias[col];
#pragma unroll
            for (int i = 0; i < 4; ++i) {
#pragma unroll
                for (int r = 0; r < 4; ++r) {
                    const int row = m0 + wm + i * 16 + quad * 4 + r;
                    of[(size_t)row * 1024 + col] = acc[i][j][r] + bv;
                }
            }
        }
    }
}

// ---------------------------------------------------------------------------
// Fallback GEMM (fp32 staging through VGPRs) — proven Round-2 path.
// ---------------------------------------------------------------------------
template <int MODE, typename AT, typename OT>
__global__ __launch_bounds__(256) void gemm_bt(const AT* __restrict__ A,
                                               const float* __restrict__ Bm,
                                               const float* __restrict__ bias,
                                               OT* __restrict__ Cout)
{
    __shared__ __align__(16) bf16 sA[128 * 32];
    __shared__ __align__(16) bf16 sB[128 * 32];
    const int tid  = threadIdx.x;
    const int lane = tid & 63;
    const int wave = tid >> 6;
    const int l15  = lane & 15;
    const int quad = lane >> 4;
    const int m0 = blockIdx.x * 128;
    const int n0 = blockIdx.y * 128;
    const int wm = (wave >> 1) * 64;
    const int wn = (wave & 1) * 64;

    f32x4 acc[4][4] = {};

    const int c0 = tid, c1 = tid + 256;
    const size_t aoff0 = (size_t)(m0 + (c0 >> 2)) * 1024 + (c0 & 3) * 8;
    const size_t aoff1 = (size_t)(m0 + (c1 >> 2)) * 1024 + (c1 & 3) * 8;
    const size_t boff0 = (size_t)(n0 + (c0 >> 2)) * 1024 + (c0 & 3) * 8;
    const size_t boff1 = (size_t)(n0 + (c1 >> 2)) * 1024 + (c1 & 3) * 8;

    for (int k0 = 0; k0 < 1024; k0 += 32) {
        stage8(&sA[c0 * 8], A  + aoff0 + k0);
        stage8(&sA[c1 * 8], A  + aoff1 + k0);
        stage8(&sB[c0 * 8], Bm + boff0 + k0);
        stage8(&sB[c1 * 8], Bm + boff1 + k0);
        __syncthreads();

        bf16x8 aF[4], bF[4];
#pragma unroll
        for (int i = 0; i < 4; ++i)
            aF[i] = *(const bf16x8*)&sA[(wm + i * 16 + l15) * 32 + quad * 8];
#pragma unroll
        for (int j = 0; j < 4; ++j)
            bF[j] = *(const bf16x8*)&sB[(wn + j * 16 + l15) * 32 + quad * 8];
#pragma unroll
        for (int i = 0; i < 4; ++i)
#pragma unroll
            for (int j = 0; j < 4; ++j)
                acc[i][j] = MFMA16(aF[i], bF[j], acc[i][j]);
        __syncthreads();
    }

#pragma unroll
    for (int j = 0; j < 4; ++j) {
        const int col = n0 + wn + j * 16 + l15;
        const float bv = bias[col];
#pragma unroll
        for (int i = 0; i < 4; ++i) {
#pragma unroll
            for (int r = 0; r < 4; ++r) {
                const int row = m0 + wm + i * 16 + quad * 4 + r;
                const float v = acc[i][j][r] + bv;
                size_t idx;
                if (MODE == 0) idx = (size_t)row * 1024 + col;
                else {
                    const int b = row >> 11, t = row & 2047;
                    const int h = col >> 6,  d = col & 63;
                    if (MODE == 1) idx = ((size_t)(b * 16 + h) * 2048 + t) * 64 + d;
                    else           idx = ((size_t)(b * 16 + h) * 64 + d) * 2048 + t;
                }
                store_out(&Cout[idx], v);
            }
        }
    }
}

// ---------------------------------------------------------------------------
// Flash attention v4: 64-key tiles (high occupancy, 27.6 KB LDS -> 5 blk/CU),
// S^T = K·Q^T, un-maxed exp2 softmax, padded conflict-free LDS, triangular
// pairing, XCD-locality swizzle: 1D grid 1024, id&7 selects the head group so
// all 16 blocks of a head share one XCD's L2 (K/V = 512 KB/head resident).
// Q,K: [B][H][T][64]; Vt: [B][H][64][T]; Y: [B][T][C] (all bf16).
// ---------------------------------------------------------------------------
__global__ __launch_bounds__(256) void attn_fwd4(const bf16* __restrict__ Q,
                                                 const bf16* __restrict__ K,
                                                 const bf16* __restrict__ Vt,
                                                 bf16* __restrict__ Y)
{
    __shared__ __align__(16) bf16 sK[64 * 72];
    __shared__ __align__(16) bf16 sV[64 * 72];       // [d][t]
    __shared__ __align__(16) bf16 sP[4][16 * 72];    // per-wave P^T [q][t]
    const int tid  = threadIdx.x;
    const int lane = tid & 63;
    const int wave = tid >> 6;
    const int l15  = lane & 15;
    const int quad = lane >> 4;

    // XCD swizzle: xcd = id&7 -> heads [xcd*8, xcd*8+8); pair = strip pair idx
    const int id   = blockIdx.x;
    const int sub  = id >> 3;            // [0,128)
    const int bh   = (id & 7) * 8 + (sub >> 4);
    const int pair = sub & 15;

    const size_t headQK = (size_t)bh * 2048 * 64;
    const size_t headV  = (size_t)bh * 64 * 2048;
    const int b = bh >> 4, h = bh & 15;
    constexpr float cscale = 0.125f * 1.44269504088896340736f;  // scale * log2(e)

    const int c0 = tid, c1 = tid + 256;
    const int r0 = c0 >> 3, col0 = (c0 & 7) * 8;
    const int r1 = c1 >> 3, col1 = (c1 & 7) * 8;
    bf16* sPw = sP[wave];

#pragma unroll
    for (int strip = 0; strip < 2; ++strip) {
        const int qt = strip ? (31 - pair) : pair;
        const int q0 = qt * 64;
        const int myq = q0 + wave * 16 + l15;

        const bf16* qrow = Q + headQK + (size_t)myq * 64;
        const bf16x8 qF0 = *(const bf16x8*)(qrow + quad * 8);
        const bf16x8 qF1 = *(const bf16x8*)(qrow + 32 + quad * 8);

        float l_part = 0.f;
        f32x4 O[4] = {};   // O^T: lane holds q=l15, d = jd*16 + quad*4 + r

        for (int t0 = 0; t0 <= q0; t0 += 64) {
            *(int4*)&sK[r0 * 72 + col0] = *(const int4*)(K + headQK + (size_t)(t0 + r0) * 64 + col0);
            *(int4*)&sK[r1 * 72 + col1] = *(const int4*)(K + headQK + (size_t)(t0 + r1) * 64 + col1);
            *(int4*)&sV[r0 * 72 + col0] = *(const int4*)(Vt + headV + (size_t)r0 * 2048 + t0 + col0);
            *(int4*)&sV[r1 * 72 + col1] = *(const int4*)(Vt + headV + (size_t)r1 * 2048 + t0 + col1);
            __syncthreads();

            const bool diag = (t0 == q0);
#pragma unroll
            for (int j = 0; j < 4; ++j) {
                // S^T sub-tile: A = K rows (m = t), B = Q rows (n = q)
                const bf16x8 kF0 = *(const bf16x8*)&sK[(j * 16 + l15) * 72 + quad * 8];
                const bf16x8 kF1 = *(const bf16x8*)&sK[(j * 16 + l15) * 72 + 32 + quad * 8];
                f32x4 zS = {};
                zS = MFMA16(kF0, qF0, zS);
                zS = MFMA16(kF1, qF1, zS);
                union { bf16 hh[4]; uint2 v; } pk;
#pragma unroll
                for (int r = 0; r < 4; ++r) {
                    float p = exp2f(zS[r] * cscale);
                    if (diag && (t0 + j * 16 + quad * 4 + r) > myq) p = 0.f;
                    l_part += p;
                    pk.hh[r] = __float2bfloat16(p);
                }
                *(uint2*)&sPw[l15 * 72 + j * 16 + quad * 4] = pk.v;
            }

            // O^T += V^T · P^T
            const bf16x8 pF0 = *(const bf16x8*)&sPw[l15 * 72 + quad * 8];
            const bf16x8 pF1 = *(const bf16x8*)&sPw[l15 * 72 + 32 + quad * 8];
#pragma unroll
            for (int jd = 0; jd < 4; ++jd) {
                const bf16x8 vF0 = *(const bf16x8*)&sV[(jd * 16 + l15) * 72 + quad * 8];
                const bf16x8 vF1 = *(const bf16x8*)&sV[(jd * 16 + l15) * 72 + 32 + quad * 8];
                O[jd] = MFMA16(vF0, pF0, O[jd]);
                O[jd] = MFMA16(vF1, pF1, O[jd]);
            }
            __syncthreads();
        }

        l_part += __shfl_xor(l_part, 16);
        l_part += __shfl_xor(l_part, 32);
        const float inv_l = 1.0f / l_part;

        bf16* yrow = Y + ((size_t)(b * 2048 + myq)) * 1024 + h * 64;
#pragma unroll
        for (int jd = 0; jd < 4; ++jd) {
            union { bf16 hh[4]; uint2 v; } ok;
#pragma unroll
            for (int r = 0; r < 4; ++r)
                ok.hh[r] = __float2bfloat16(O[jd][r] * inv_l);
            *(uint2*)&yrow[jd * 16 + quad * 4] = ok.v;
        }
    }
}

// ---------------------------------------------------------------------------
extern "C" void kernel_launch(void* const* d_in, const int* in_sizes, int n_in,
                              void* d_out, int out_size, void* d_ws, size_t ws_size,
                              hipStream_t stream)
{
    const float* x  = (const float*)d_in[0];
    const float* Wq = (const float*)d_in[1];
    const float* bq = (const float*)d_in[2];
    const float* Wk = (const float*)d_in[3];
    const float* bk = (const float*)d_in[4];
    const float* Wv = (const float*)d_in[5];
    const float* bv = (const float*)d_in[6];
    const float* Wp = (const float*)d_in[7];
    const float* bp = (const float*)d_in[8];
    float* out = (float*)d_out;
    bf16*  ws  = (bf16*)d_ws;

    constexpr size_t NE = (size_t)8192 * 1024;  // 8M elems per [B,T,C] tensor
    bf16* Qw = ws;
    bf16* Kw = ws + NE;
    bf16* Vw = ws + 2 * NE;      // [B][H][D][T]
    dim3 bb(256);

    if (ws_size >= (size_t)36 * 1024 * 1024 * 2) {
        bf16* xb = ws + 3 * NE;                  // aliased with Yw (x dead after QKV)
        bf16* Wb = ws + 4 * NE;                  // 4 x 1M bf16 weights
        bf16* Yw = xb;

        cvt_bf16<<<dim3(1024), bb, 0, stream>>>(x, Wq, Wk, Wv, Wp, xb, Wb);

        GemmArgs gq;
        gq.Bm[0] = Wb;    gq.Bm[1] = Wb + (1u << 20);  gq.Bm[2] = Wb + (2u << 20);
        gq.bias[0] = bq;  gq.bias[1] = bk;             gq.bias[2] = bv;
        gq.out[0] = Qw;   gq.out[1] = Kw;              gq.out[2] = Vw;
        gq.mode[0] = 1;   gq.mode[1] = 1;              gq.mode[2] = 2;
        gemm_bb<<<dim3(1536), bb, 0, stream>>>(xb, gq);

        attn_fwd4<<<dim3(1024), bb, 0, stream>>>(Qw, Kw, Vw, Yw);

        GemmArgs go;
        go.Bm[0] = go.Bm[1] = go.Bm[2] = Wb + ((size_t)3 << 20);
        go.bias[0] = go.bias[1] = go.bias[2] = bp;
        go.out[0] = go.out[1] = go.out[2] = out;
        go.mode[0] = go.mode[1] = go.mode[2] = 0;
        gemm_bb<<<dim3(512), bb, 0, stream>>>(Yw, go);
    } else {
        bf16* Yw = ws + 3 * NE;
        dim3 gg(64, 8);
        gemm_bt<1, float, bf16><<<gg, bb, 0, stream>>>(x, Wq, bq, Qw);
        gemm_bt<1, float, bf16><<<gg, bb, 0, stream>>>(x, Wk, bk, Kw);
        gemm_bt<2, float, bf16><<<gg, bb, 0, stream>>>(x, Wv, bv, Vw);
        attn_fwd4<<<dim3(1024), bb, 0, stream>>>(Qw, Kw, Vw, Yw);
        gemm_bt<0, bf16, float><<<gg, bb, 0, stream>>>(Yw, Wp, bp, out);
    }
}